// Round 6
// baseline (161.134 us; speedup 1.0000x reference)
//
#include <hip/hip_runtime.h>

// SpatialEncoding: out[b,n1,n2] = weight[path_distance_map[b,e]] for the
// LAST e with edge_index_map[b,e]=(n1,n2); else weight[511].
//
// Round 6 == round 5 with the nontemporal builtins fixed to use
// ext_vector_type (HIP_vector_type classes are rejected by the builtin):
//  - bin reads pdm/eim with nontemporal loads (read-once -> don't evict
//    the record region from LLC)
//  - resolve reads records nontemporal and writes the 268MB output with
//    nontemporal stores (write-once -> don't evict not-yet-read records)
// Last-write-wins via max over packed (e<<9|d): order-independent ->
// deterministic across graph replays despite nondeterministic bin order.

#define BB 64
#define TT 1024
#define EE 200000
#define MAXD 512
#define GRP 8               // rows per bucket (resolve tile height)
#define NG  (TT / GRP)      // 128 buckets per batch
#define CAPR 4096           // int2 records per bucket region (== 32KB == GRP rows)
#define CPB 2048            // edges per bin block
#define EPT 8               // edges per thread (256 threads)

typedef int   vi4 __attribute__((ext_vector_type(4)));
typedef int   vi2 __attribute__((ext_vector_type(2)));
typedef float vf4 __attribute__((ext_vector_type(4)));

__global__ void __launch_bounds__(256)
bin_kernel(const int* __restrict__ pdm,
           const int* __restrict__ eim,
           int* __restrict__ gcnt,       // [BB*NG] global bucket counters
           int2* __restrict__ grecs) {   // d_out viewed as record slots
    __shared__ int hist[NG], prefix[NG], resv[NG];
    __shared__ int wsum[2];
    __shared__ int2 rec[CPB];
    __shared__ int dst[CPB];
    const int tid = threadIdx.x;
    const int b = blockIdx.y;
    const int e0 = blockIdx.x * CPB + tid * EPT;

    for (int i = tid; i < NG; i += 256) hist[i] = 0;
    __syncthreads();

    // ---- load 8 contiguous edges per thread (vectorized, nontemporal) ----
    int dvals[EPT]; int2 nvals[EPT]; int nv;
    const int* pb = pdm + (size_t)b * EE;
    const int2* ebp = ((const int2*)eim) + (size_t)b * EE;
    if (e0 + EPT <= EE) {
        const vi4* p4 = (const vi4*)(pb + e0);
        vi4 pA = __builtin_nontemporal_load(p4);
        vi4 pB = __builtin_nontemporal_load(p4 + 1);
        dvals[0]=pA.x; dvals[1]=pA.y; dvals[2]=pA.z; dvals[3]=pA.w;
        dvals[4]=pB.x; dvals[5]=pB.y; dvals[6]=pB.z; dvals[7]=pB.w;
        const vi4* e4 = (const vi4*)(ebp + e0);
        vi4 eA = __builtin_nontemporal_load(e4);
        vi4 eB = __builtin_nontemporal_load(e4 + 1);
        vi4 eC = __builtin_nontemporal_load(e4 + 2);
        vi4 eD = __builtin_nontemporal_load(e4 + 3);
        nvals[0]=make_int2(eA.x,eA.y); nvals[1]=make_int2(eA.z,eA.w);
        nvals[2]=make_int2(eB.x,eB.y); nvals[3]=make_int2(eB.z,eB.w);
        nvals[4]=make_int2(eC.x,eC.y); nvals[5]=make_int2(eC.z,eC.w);
        nvals[6]=make_int2(eD.x,eD.y); nvals[7]=make_int2(eD.z,eD.w);
        nv = EPT;
    } else {
        nv = EE - e0; if (nv < 0) nv = 0; if (nv > EPT) nv = EPT;
        #pragma unroll
        for (int k = 0; k < EPT; ++k)
            if (k < nv) { dvals[k] = pb[e0 + k]; nvals[k] = ebp[e0 + k]; }
    }

    // ---- LDS histogram; per-edge rank within (block,bucket) ----
    int g[EPT], rk[EPT];
    #pragma unroll
    for (int k = 0; k < EPT; ++k) {
        if (k < nv) {
            g[k] = nvals[k].x >> 3;          // n1 / GRP
            rk[k] = atomicAdd(&hist[g[k]], 1);
        }
    }
    __syncthreads();

    // ---- exclusive scan over NG=128 (two wave64 shuffle scans + fixup)
    //      + ONE global reserve per bucket ----
    if (tid < NG) {
        int v = hist[tid], inc = v;
        #pragma unroll
        for (int off = 1; off < 64; off <<= 1) {
            int t = __shfl_up(inc, off);
            if ((tid & 63) >= off) inc += t;
        }
        if ((tid & 63) == 63) wsum[tid >> 6] = inc;
        prefix[tid] = inc - v;
        resv[tid] = atomicAdd(&gcnt[b * NG + tid], v);
    }
    __syncthreads();
    if (tid >= 64 && tid < NG) prefix[tid] += wsum[0];
    __syncthreads();

    // ---- reorder records by bucket in LDS; precompute global slots ----
    #pragma unroll
    for (int k = 0; k < EPT; ++k) {
        if (k < nv) {
            int e = e0 + k;
            int lp = prefix[g[k]] + rk[k];
            rec[lp] = make_int2(((nvals[k].x & (GRP - 1)) << 10) | nvals[k].y,
                                (e << 9) | dvals[k]);
            int gp = resv[g[k]] + rk[k];
            dst[lp] = (gp < CAPR) ? (((b * NG + g[k]) << 12) | gp) : -1;
        }
    }
    __syncthreads();

    // ---- copy out: bucket-ordered -> contiguous runs, good coalescing ----
    int total = EE - blockIdx.x * CPB;
    if (total > CPB) total = CPB;
    for (int j = tid; j < total; j += 256) {
        int dd = dst[j];
        if (dd >= 0) {
            vi2 v; v.x = rec[j].x; v.y = rec[j].y;
            __builtin_nontemporal_store(v,
                (vi2*)&grecs[((size_t)(dd >> 12) << 12) | (dd & (CAPR - 1))]);
        }
    }
}

__global__ void __launch_bounds__(512)
resolve_kernel(const float* __restrict__ w,
               const int* __restrict__ gcnt,
               float* __restrict__ out) {
    __shared__ int tile[GRP * TT];     // 32 KB
    __shared__ float sw[MAXD];         // 2 KB
    const int tid = threadIdx.x;
    const int q = blockIdx.x;          // bucket id = b*NG + g

    for (int i = tid; i < MAXD; i += 512) sw[i] = w[i];
    int4* t4 = (int4*)tile;
    for (int i = tid; i < GRP * TT / 4; i += 512)
        t4[i] = make_int4(-1, -1, -1, -1);
    __syncthreads();

    int c = gcnt[q]; if (c > CAPR) c = CAPR;
    const vi2* recs = (const vi2*)(((const int2*)out) + ((size_t)q * CAPR));
    for (int i = tid; i < c; i += 512) {
        vi2 r = __builtin_nontemporal_load(&recs[i]);
        atomicMax(&tile[r.x], r.y);    // r.x = (row_in_grp<<10)|n2
    }
    __syncthreads();

    // overwrite this bucket's 32KB output region (record reads are done);
    // nontemporal: write-once, keep LLC for other blocks' records
    vf4* o4 = (vf4*)(out + (size_t)q * (GRP * TT));
    for (int i = tid; i < GRP * TT / 4; i += 512) {
        int4 v = t4[i];
        vf4 r;
        r.x = sw[v.x < 0 ? (MAXD - 1) : (v.x & (MAXD - 1))];
        r.y = sw[v.y < 0 ? (MAXD - 1) : (v.y & (MAXD - 1))];
        r.z = sw[v.z < 0 ? (MAXD - 1) : (v.z & (MAXD - 1))];
        r.w = sw[v.w < 0 ? (MAXD - 1) : (v.w & (MAXD - 1))];
        __builtin_nontemporal_store(r, &o4[i]);
    }
}

// ---- fallback (round-1 algorithm) if d_ws is unexpectedly tiny ----

__global__ void __launch_bounds__(256)
scatter_max_kernel(const int* __restrict__ pdm,
                   const int* __restrict__ eim,
                   int* __restrict__ outi) {
    int e = blockIdx.x * blockDim.x + threadIdx.x;
    int b = blockIdx.y;
    if (e >= EE) return;
    int d = pdm[(size_t)b * EE + e];
    int2 n = ((const int2*)eim)[(size_t)b * EE + e];
    atomicMax(&outi[((size_t)b * TT + (size_t)n.x) * TT + (size_t)n.y],
              (e << 9) | d);
}

__global__ void __launch_bounds__(256)
finalize_kernel(const float* __restrict__ w, float* __restrict__ out, size_t n4) {
    const size_t stride = (size_t)gridDim.x * blockDim.x;
    int4* pi = (int4*)out;
    float4* pf = (float4*)out;
    for (size_t i = (size_t)blockIdx.x * blockDim.x + threadIdx.x; i < n4; i += stride) {
        int4 v = pi[i];
        float4 r;
        r.x = w[v.x < 0 ? (MAXD - 1) : (v.x & (MAXD - 1))];
        r.y = w[v.y < 0 ? (MAXD - 1) : (v.y & (MAXD - 1))];
        r.z = w[v.z < 0 ? (MAXD - 1) : (v.z & (MAXD - 1))];
        r.w = w[v.w < 0 ? (MAXD - 1) : (v.w & (MAXD - 1))];
        pf[i] = r;
    }
}

extern "C" void kernel_launch(void* const* d_in, const int* in_sizes, int n_in,
                              void* d_out, int out_size, void* d_ws, size_t ws_size,
                              hipStream_t stream) {
    const float* w   = (const float*)d_in[1];
    const int*   pdm = (const int*)d_in[2];
    const int*   eim = (const int*)d_in[3];
    float* out = (float*)d_out;

    const size_t cnt_bytes = (size_t)BB * NG * sizeof(int);   // 32 KB

    if (ws_size >= cnt_bytes) {
        (void)hipMemsetAsync(d_ws, 0, cnt_bytes, stream);
        dim3 bgrid((EE + CPB - 1) / CPB, BB);                 // (98, 64)
        bin_kernel<<<bgrid, 256, 0, stream>>>(pdm, eim, (int*)d_ws, (int2*)d_out);
        resolve_kernel<<<BB * NG, 512, 0, stream>>>(w, (const int*)d_ws, out);
    } else {
        (void)hipMemsetAsync(d_out, 0xFF, (size_t)out_size * sizeof(float), stream);
        dim3 sgrid((EE + 255) / 256, BB);
        scatter_max_kernel<<<sgrid, 256, 0, stream>>>(pdm, eim, (int*)d_out);
        finalize_kernel<<<2048, 256, 0, stream>>>(w, out, (size_t)out_size / 4);
    }
}

// Round 7
// 123.747 us; speedup vs baseline: 1.3021x; 1.3021x over previous
//
#include <hip/hip_runtime.h>

// SpatialEncoding: out[b,n1,n2] = weight[path_distance_map[b,e]] for the
// LAST e with edge_index_map[b,e]=(n1,n2); else weight[511].
//
// Round 7: round-4 structure (NT hints reverted — they pushed the record
// round-trip out of LLC and cost +37us), plus latency-shaving:
//  - resolve: issue-early/apply-late — all record loads (4x int4/thread,
//    covers CAPR exactly) issued BEFORE tile init; apply after barrier.
//  - bin: input loads issued BEFORE histogram zeroing so HBM latency
//    hides under LDS init + barrier.
// Last-write-wins via max over packed (e<<9|d): order-independent ->
// deterministic across graph replays despite nondeterministic bin order.

#define BB 64
#define TT 1024
#define EE 200000
#define MAXD 512
#define GRP 8               // rows per bucket (resolve tile height)
#define NG  (TT / GRP)      // 128 buckets per batch
#define CAPR 4096           // int2 records per bucket region (== 32KB == GRP rows)
#define CPB 2048            // edges per bin block
#define EPT 8               // edges per thread (256 threads)

__global__ void __launch_bounds__(256)
bin_kernel(const int* __restrict__ pdm,
           const int* __restrict__ eim,
           int* __restrict__ gcnt,       // [BB*NG] global bucket counters
           int2* __restrict__ grecs) {   // d_out viewed as record slots
    __shared__ int hist[NG], prefix[NG], resv[NG];
    __shared__ int wsum[2];
    __shared__ int2 rec[CPB];
    __shared__ int dst[CPB];
    const int tid = threadIdx.x;
    const int b = blockIdx.y;
    const int e0 = blockIdx.x * CPB + tid * EPT;

    // ---- issue input loads FIRST (latency hides under hist init) ----
    int dvals[EPT]; int2 nvals[EPT]; int nv;
    const int* pb = pdm + (size_t)b * EE;
    const int2* ebp = ((const int2*)eim) + (size_t)b * EE;
    if (e0 + EPT <= EE) {
        const int4* p4 = (const int4*)(pb + e0);
        int4 pA = p4[0], pB = p4[1];
        const int4* e4 = (const int4*)(ebp + e0);
        int4 eA = e4[0], eB = e4[1], eC = e4[2], eD = e4[3];
        dvals[0]=pA.x; dvals[1]=pA.y; dvals[2]=pA.z; dvals[3]=pA.w;
        dvals[4]=pB.x; dvals[5]=pB.y; dvals[6]=pB.z; dvals[7]=pB.w;
        nvals[0]=make_int2(eA.x,eA.y); nvals[1]=make_int2(eA.z,eA.w);
        nvals[2]=make_int2(eB.x,eB.y); nvals[3]=make_int2(eB.z,eB.w);
        nvals[4]=make_int2(eC.x,eC.y); nvals[5]=make_int2(eC.z,eC.w);
        nvals[6]=make_int2(eD.x,eD.y); nvals[7]=make_int2(eD.z,eD.w);
        nv = EPT;
    } else {
        nv = EE - e0; if (nv < 0) nv = 0; if (nv > EPT) nv = EPT;
        #pragma unroll
        for (int k = 0; k < EPT; ++k)
            if (k < nv) { dvals[k] = pb[e0 + k]; nvals[k] = ebp[e0 + k]; }
    }

    for (int i = tid; i < NG; i += 256) hist[i] = 0;
    __syncthreads();

    // ---- LDS histogram; per-edge rank within (block,bucket) ----
    int g[EPT], rk[EPT];
    #pragma unroll
    for (int k = 0; k < EPT; ++k) {
        if (k < nv) {
            g[k] = nvals[k].x >> 3;          // n1 / GRP
            rk[k] = atomicAdd(&hist[g[k]], 1);
        }
    }
    __syncthreads();

    // ---- exclusive scan over NG=128 (two wave64 shuffle scans + fixup)
    //      + ONE global reserve per bucket ----
    if (tid < NG) {
        int v = hist[tid], inc = v;
        #pragma unroll
        for (int off = 1; off < 64; off <<= 1) {
            int t = __shfl_up(inc, off);
            if ((tid & 63) >= off) inc += t;
        }
        if ((tid & 63) == 63) wsum[tid >> 6] = inc;
        prefix[tid] = inc - v;
        resv[tid] = atomicAdd(&gcnt[b * NG + tid], v);
    }
    __syncthreads();
    if (tid >= 64 && tid < NG) prefix[tid] += wsum[0];
    __syncthreads();

    // ---- reorder records by bucket in LDS; precompute global slots ----
    #pragma unroll
    for (int k = 0; k < EPT; ++k) {
        if (k < nv) {
            int e = e0 + k;
            int lp = prefix[g[k]] + rk[k];
            rec[lp] = make_int2(((nvals[k].x & (GRP - 1)) << 10) | nvals[k].y,
                                (e << 9) | dvals[k]);
            int gp = resv[g[k]] + rk[k];
            dst[lp] = (gp < CAPR) ? (((b * NG + g[k]) << 12) | gp) : -1;
        }
    }
    __syncthreads();

    // ---- copy out: bucket-ordered -> contiguous runs, good coalescing ----
    int total = EE - blockIdx.x * CPB;
    if (total > CPB) total = CPB;
    for (int j = tid; j < total; j += 256) {
        int dd = dst[j];
        if (dd >= 0)
            grecs[((size_t)(dd >> 12) << 12) | (dd & (CAPR - 1))] = rec[j];
    }
}

__global__ void __launch_bounds__(512)
resolve_kernel(const float* __restrict__ w,
               const int* __restrict__ gcnt,
               float* __restrict__ out) {
    __shared__ int tile[GRP * TT];     // 32 KB
    __shared__ float sw[MAXD];         // 2 KB
    const int tid = threadIdx.x;
    const int q = blockIdx.x;          // bucket id = b*NG + g

    // ---- issue-early: all record loads in flight before tile init ----
    int c = gcnt[q]; if (c > CAPR) c = CAPR;
    const int4* recs4 = (const int4*)(((const int2*)out) + ((size_t)q * CAPR));
    int4 pre[4];                       // 4 x (2 records) x 512 thr = CAPR
    #pragma unroll
    for (int k = 0; k < 4; ++k) {
        int i4 = tid + k * 512;        // record pair index
        if (2 * i4 < c) pre[k] = recs4[i4];
    }

    for (int i = tid; i < MAXD; i += 512) sw[i] = w[i];
    int4* t4 = (int4*)tile;
    for (int i = tid; i < GRP * TT / 4; i += 512)
        t4[i] = make_int4(-1, -1, -1, -1);
    __syncthreads();

    // ---- apply-late: LDS atomicMax from registers ----
    #pragma unroll
    for (int k = 0; k < 4; ++k) {
        int i4 = tid + k * 512;
        int r0 = 2 * i4, r1 = 2 * i4 + 1;
        if (r0 < c) atomicMax(&tile[pre[k].x], pre[k].y);
        if (r1 < c) atomicMax(&tile[pre[k].z], pre[k].w);
    }
    __syncthreads();

    // overwrite this bucket's 32KB output region (record reads are done)
    float4* o4 = (float4*)(out + (size_t)q * (GRP * TT));
    for (int i = tid; i < GRP * TT / 4; i += 512) {
        int4 v = t4[i];
        float4 r;
        r.x = sw[v.x < 0 ? (MAXD - 1) : (v.x & (MAXD - 1))];
        r.y = sw[v.y < 0 ? (MAXD - 1) : (v.y & (MAXD - 1))];
        r.z = sw[v.z < 0 ? (MAXD - 1) : (v.z & (MAXD - 1))];
        r.w = sw[v.w < 0 ? (MAXD - 1) : (v.w & (MAXD - 1))];
        o4[i] = r;
    }
}

// ---- fallback (round-1 algorithm) if d_ws is unexpectedly tiny ----

__global__ void __launch_bounds__(256)
scatter_max_kernel(const int* __restrict__ pdm,
                   const int* __restrict__ eim,
                   int* __restrict__ outi) {
    int e = blockIdx.x * blockDim.x + threadIdx.x;
    int b = blockIdx.y;
    if (e >= EE) return;
    int d = pdm[(size_t)b * EE + e];
    int2 n = ((const int2*)eim)[(size_t)b * EE + e];
    atomicMax(&outi[((size_t)b * TT + (size_t)n.x) * TT + (size_t)n.y],
              (e << 9) | d);
}

__global__ void __launch_bounds__(256)
finalize_kernel(const float* __restrict__ w, float* __restrict__ out, size_t n4) {
    const size_t stride = (size_t)gridDim.x * blockDim.x;
    int4* pi = (int4*)out;
    float4* pf = (float4*)out;
    for (size_t i = (size_t)blockIdx.x * blockDim.x + threadIdx.x; i < n4; i += stride) {
        int4 v = pi[i];
        float4 r;
        r.x = w[v.x < 0 ? (MAXD - 1) : (v.x & (MAXD - 1))];
        r.y = w[v.y < 0 ? (MAXD - 1) : (v.y & (MAXD - 1))];
        r.z = w[v.z < 0 ? (MAXD - 1) : (v.z & (MAXD - 1))];
        r.w = w[v.w < 0 ? (MAXD - 1) : (v.w & (MAXD - 1))];
        pf[i] = r;
    }
}

extern "C" void kernel_launch(void* const* d_in, const int* in_sizes, int n_in,
                              void* d_out, int out_size, void* d_ws, size_t ws_size,
                              hipStream_t stream) {
    const float* w   = (const float*)d_in[1];
    const int*   pdm = (const int*)d_in[2];
    const int*   eim = (const int*)d_in[3];
    float* out = (float*)d_out;

    const size_t cnt_bytes = (size_t)BB * NG * sizeof(int);   // 32 KB

    if (ws_size >= cnt_bytes) {
        (void)hipMemsetAsync(d_ws, 0, cnt_bytes, stream);
        dim3 bgrid((EE + CPB - 1) / CPB, BB);                 // (98, 64)
        bin_kernel<<<bgrid, 256, 0, stream>>>(pdm, eim, (int*)d_ws, (int2*)d_out);
        resolve_kernel<<<BB * NG, 512, 0, stream>>>(w, (const int*)d_ws, out);
    } else {
        (void)hipMemsetAsync(d_out, 0xFF, (size_t)out_size * sizeof(float), stream);
        dim3 sgrid((EE + 255) / 256, BB);
        scatter_max_kernel<<<sgrid, 256, 0, stream>>>(pdm, eim, (int*)d_out);
        finalize_kernel<<<2048, 256, 0, stream>>>(w, out, (size_t)out_size / 4);
    }
}